// Round 4
// baseline (1898.354 us; speedup 1.0000x reference)
//
#include <hip/hip_runtime.h>
#include <hip/hip_bf16.h>
#include <cstdint>
#include <cstddef>

typedef short bf16x8 __attribute__((ext_vector_type(8)));
typedef float f32x4 __attribute__((ext_vector_type(4)));

static __device__ __forceinline__ unsigned short f2bf(float f) {
    union { float f; uint32_t u; } c; c.f = f;
    uint32_t r = c.u + 0x7FFFu + ((c.u >> 16) & 1u);
    return (unsigned short)(r >> 16);
}
static __device__ __forceinline__ float bf2f_lo(uint32_t w) {
    union { uint32_t u; float f; } c; c.u = w << 16; return c.f;
}
static __device__ __forceinline__ float bf2f_hi(uint32_t w) {
    union { uint32_t u; float f; } c; c.u = w & 0xffff0000u; return c.f;
}
static __device__ __forceinline__ float fast_tanh(float x) {
    float e = __expf(2.0f * x);
    return 1.0f - 2.0f / (e + 1.0f);
}
static __device__ __forceinline__ float softplus_f(float x) {
    return fmaxf(x, 0.0f) + log1pf(__expf(-fabsf(x)));
}

// ---------------- f32 -> bf16 conversion, 5 segments in one launch ----------
__global__ __launch_bounds__(256) void k_convert(
    const float* __restrict__ s0, const float* __restrict__ s1,
    const float* __restrict__ s2, const float* __restrict__ s3,
    const float* __restrict__ s4,
    unsigned short* __restrict__ d0, unsigned short* __restrict__ d1,
    unsigned short* __restrict__ d2, unsigned short* __restrict__ d3,
    unsigned short* __restrict__ d4,
    int n0, int n1, int n2, int n3, int n4)
{
    int i = blockIdx.x * 256 + threadIdx.x; // float4 index
    int c0 = n0 >> 2, c1 = c0 + (n1 >> 2), c2 = c1 + (n2 >> 2),
        c3 = c2 + (n3 >> 2), c4 = c3 + (n4 >> 2);
    if (i >= c4) return;
    const float* s; unsigned short* d; int j;
    if (i < c0)      { s = s0; d = d0; j = i; }
    else if (i < c1) { s = s1; d = d1; j = i - c0; }
    else if (i < c2) { s = s2; d = d2; j = i - c1; }
    else if (i < c3) { s = s3; d = d3; j = i - c2; }
    else             { s = s4; d = d4; j = i - c3; }
    float4 v = reinterpret_cast<const float4*>(s)[j];
    ushort4 o;
    o.x = f2bf(v.x); o.y = f2bf(v.y); o.z = f2bf(v.z); o.w = f2bf(v.w);
    reinterpret_cast<ushort4*>(d)[j] = o;
}

// ---------------- projection GEMM: out[m,f] = sum_d A[m,d]*W[f,d] + bias[f] --
__global__ __launch_bounds__(256) void k_proj(
    const unsigned short* __restrict__ A,   // [M][512] bf16
    const unsigned short* __restrict__ W,   // [1024][512] bf16
    const float* __restrict__ bias,         // [1024]
    float* __restrict__ out)                // [M][1024] f32
{
    __shared__ unsigned short As[32 * 512];
    const int tid = threadIdx.x;
    const int m0 = blockIdx.x * 32;
    const int c0 = blockIdx.y * 128;
    {
        int row = tid >> 3;
        const unsigned short* src = A + (size_t)(m0 + row) * 512;
        unsigned int base = row * 1024;
        unsigned int sw = (row & 7) << 4;
        #pragma unroll
        for (int c = 0; c < 8; ++c) {
            int col = (tid & 7) * 8 + c * 64;
            bf16x8 v = *reinterpret_cast<const bf16x8*>(src + col);
            *reinterpret_cast<bf16x8*>(
                reinterpret_cast<char*>(As) + ((base + col * 2) ^ sw)) = v;
        }
    }
    __syncthreads();
    const int w = tid >> 6, l = tid & 63;
    const int lr = l & 15, lkb = (l >> 4) * 8;
    f32x4 acc[2][2] = {};
    const int colbase = c0 + w * 32;
    const unsigned short* Wb = W + (size_t)(colbase + lr) * 512 + lkb;
    const unsigned int sw = (lr & 7) << 4;
    for (int ks = 0; ks < 16; ++ks) {
        unsigned int kb = (ks * 32 + lkb) * 2;
        bf16x8 a0 = *reinterpret_cast<const bf16x8*>(
            reinterpret_cast<const char*>(As) + ((lr * 1024 + kb) ^ sw));
        bf16x8 a1 = *reinterpret_cast<const bf16x8*>(
            reinterpret_cast<const char*>(As) + (((16 + lr) * 1024 + kb) ^ sw));
        #pragma unroll
        for (int nf = 0; nf < 2; ++nf) {
            bf16x8 b = *reinterpret_cast<const bf16x8*>(Wb + nf * 16 * 512 + ks * 32);
            acc[0][nf] = __builtin_amdgcn_mfma_f32_16x16x32_bf16(a0, b, acc[0][nf], 0, 0, 0);
            acc[1][nf] = __builtin_amdgcn_mfma_f32_16x16x32_bf16(a1, b, acc[1][nf], 0, 0, 0);
        }
    }
    const int qr = (l >> 4) * 4;
    #pragma unroll
    for (int nf = 0; nf < 2; ++nf) {
        int col = colbase + nf * 16 + lr;
        float bv = bias[col];
        #pragma unroll
        for (int mf = 0; mf < 2; ++mf)
            #pragma unroll
            for (int r = 0; r < 4; ++r)
                out[(size_t)(m0 + mf * 16 + qr + r) * 1024 + col] = acc[mf][nf][r] + bv;
    }
}

// ---------------- fused joint kernel ----------------------------------------
// 1000 blocks x 1024 thr (16 waves, 4/SIMD). M_tile=128 rows. V split into two
// sequential 512-col passes -> acc = 4x4 f32x4 = 64 regs/lane. Per pass: K=1024
// in 2 LDS A-halves (128x512 bf16, tanh fused, XOR-swizzled); barrier-free
// K-loop streams wave-private B (64 cols/wave) from L2 with reg ping-pong.
// Pass 0 stashes biased logits bf16 (lane-private, coalesced) in out's upper
// half; pass 1 reads stash + does combined blank/log-softmax epilogue.
__global__ __launch_bounds__(1024, 4) void k_main(
    const float* __restrict__ enc,            // [1600][1024] f32
    const float* __restrict__ dec,            // [320][1024] f32
    const unsigned short* __restrict__ Wfc,   // [1024][1024] bf16
    const float* __restrict__ bfc,            // [1024]
    float* __restrict__ out)                  // [128000][1024] f32
{
    extern __shared__ char smem[];
    char*  As   = smem;                      // 128 rows x 1024 B (one K-half)
    float* red  = (float*)(smem + 131072);   // [128][8]
    float* Mc   = (float*)(smem + 135168);   // [128]
    float* fin  = (float*)(smem + 135680);   // [128]
    float* f0sh = (float*)(smem + 136192);   // [128]
    float* l0sh = (float*)(smem + 136704);   // [128]

    const int tid = threadIdx.x;
    const int w = tid >> 6, l = tid & 63;
    const int lr = l & 15, q = l >> 4;
    const int wm = w >> 3, wn = w & 7;

    // XCD-aware bijective swizzle: 1000 blocks = 8 XCDs x 125
    const int bid = (int)blockIdx.x;
    const int sbid = (bid & 7) * 125 + (bid >> 3);
    const int r0 = sbid * 128;

    // A-build mapping: row = tid>>3, k-lane = tid&7 (8 elems x 8 stripes)
    const int arow = tid >> 3, akc = tid & 7;
    const float *ep, *dp;
    {
        int m = r0 + arow;
        int bt = m / 80;
        int u = m - bt * 80;
        int b = bt / 400;
        ep = enc + (size_t)bt * 1024 + akc * 8;
        dp = dec + (size_t)(b * 80 + u) * 1024 + akc * 8;
    }
    const unsigned awbase = (unsigned)(arow * 1024 + akc * 16);
    const unsigned awkey  = (unsigned)((arow & 7) << 4);

    // A-frag read base (unswizzled) + key; mf*16384 goes in the imm offset
    const unsigned abase = (unsigned)((wm * 64 + lr) * 1024 + q * 16);
    const unsigned akey  = (unsigned)((lr & 7) << 4);

    // lane-private stash region: out[r0..][512..], byte off = w*8192+i*1024+l*16
    char* stash = (char*)(out + (size_t)r0 * 1024 + 512) + w * 8192 + l * 16;

    #pragma unroll
    for (int vp = 0; vp < 2; ++vp) {
        const unsigned short* Wv =
            Wfc + (size_t)(vp * 512 + wn * 64 + lr) * 1024 + q * 8;
        f32x4 acc[4][4] = {};
        bf16x8 Bp0[4], Bp1[4];
        #pragma unroll
        for (int nf = 0; nf < 4; ++nf) Bp0[nf] = *(const bf16x8*)(Wv + nf * 16384);
        #pragma unroll
        for (int nf = 0; nf < 4; ++nf) Bp1[nf] = *(const bf16x8*)(Wv + nf * 16384 + 32);

        #pragma unroll
        for (int kh = 0; kh < 2; ++kh) {
            __syncthreads();                    // As safe to overwrite
            {   // build A half kh: tanh(enc+dec) -> bf16 -> swizzled LDS
                const float* eph = ep + kh * 512;
                const float* dph = dp + kh * 512;
                #pragma unroll
                for (int c = 0; c < 8; ++c) {
                    float4 e0 = *(const float4*)(eph + c * 64);
                    float4 e1 = *(const float4*)(eph + c * 64 + 4);
                    float4 f0 = *(const float4*)(dph + c * 64);
                    float4 f1 = *(const float4*)(dph + c * 64 + 4);
                    union { unsigned short h[8]; bf16x8 v; } pk;
                    pk.h[0] = f2bf(fast_tanh(e0.x + f0.x));
                    pk.h[1] = f2bf(fast_tanh(e0.y + f0.y));
                    pk.h[2] = f2bf(fast_tanh(e0.z + f0.z));
                    pk.h[3] = f2bf(fast_tanh(e0.w + f0.w));
                    pk.h[4] = f2bf(fast_tanh(e1.x + f1.x));
                    pk.h[5] = f2bf(fast_tanh(e1.y + f1.y));
                    pk.h[6] = f2bf(fast_tanh(e1.z + f1.z));
                    pk.h[7] = f2bf(fast_tanh(e1.w + f1.w));
                    *(bf16x8*)(As + ((awbase + c * 128) ^ awkey)) = pk.v;
                }
            }
            __syncthreads();
            // barrier-free K-loop over this half (16 steps of 32)
            #pragma unroll
            for (int kp = 0; kp < 8; ++kp) {
                {   // even step
                    const int ks = kp * 2, gks = kh * 16 + ks;
                    bf16x8 a[4];
                    unsigned ao = (abase + ks * 64) ^ akey;
                    #pragma unroll
                    for (int mf = 0; mf < 4; ++mf)
                        a[mf] = *(const bf16x8*)(As + ao + mf * 16384);
                    #pragma unroll
                    for (int nf = 0; nf < 4; ++nf) {
                        #pragma unroll
                        for (int mf = 0; mf < 4; ++mf)
                            acc[mf][nf] = __builtin_amdgcn_mfma_f32_16x16x32_bf16(
                                a[mf], Bp0[nf], acc[mf][nf], 0, 0, 0);
                        if (gks + 2 < 32)
                            Bp0[nf] = *(const bf16x8*)(Wv + nf * 16384 + (gks + 2) * 32);
                    }
                }
                {   // odd step
                    const int ks = kp * 2 + 1, gks = kh * 16 + ks;
                    bf16x8 a[4];
                    unsigned ao = (abase + ks * 64) ^ akey;
                    #pragma unroll
                    for (int mf = 0; mf < 4; ++mf)
                        a[mf] = *(const bf16x8*)(As + ao + mf * 16384);
                    #pragma unroll
                    for (int nf = 0; nf < 4; ++nf) {
                        #pragma unroll
                        for (int mf = 0; mf < 4; ++mf)
                            acc[mf][nf] = __builtin_amdgcn_mfma_f32_16x16x32_bf16(
                                a[mf], Bp1[nf], acc[mf][nf], 0, 0, 0);
                        if (gks + 2 < 32)
                            Bp1[nf] = *(const bf16x8*)(Wv + nf * 16384 + (gks + 2) * 32);
                    }
                }
            }
        }

        if (vp == 0) {
            // add bias, pack to bf16 words, coalesced stash store
            #pragma unroll
            for (int nf = 0; nf < 4; ++nf) {
                float bv = bfc[wn * 64 + nf * 16 + lr];
                #pragma unroll
                for (int mf = 0; mf < 4; ++mf)
                    #pragma unroll
                    for (int r = 0; r < 4; ++r)
                        acc[mf][nf][r] += bv;
            }
            uint32_t wds[32];
            #pragma unroll
            for (int mf = 0; mf < 4; ++mf)
                #pragma unroll
                for (int nf = 0; nf < 4; ++nf) {
                    wds[mf * 8 + nf * 2 + 0] =
                        (uint32_t)f2bf(acc[mf][nf][0]) | ((uint32_t)f2bf(acc[mf][nf][1]) << 16);
                    wds[mf * 8 + nf * 2 + 1] =
                        (uint32_t)f2bf(acc[mf][nf][2]) | ((uint32_t)f2bf(acc[mf][nf][3]) << 16);
                }
            #pragma unroll
            for (int i = 0; i < 8; ++i) {
                uint4 v = { wds[4*i], wds[4*i+1], wds[4*i+2], wds[4*i+3] };
                *(uint4*)(stash + i * 1024) = v;
            }
        } else {
            // read stash back (lane-private)
            uint32_t wds[32];
            #pragma unroll
            for (int i = 0; i < 8; ++i) {
                uint4 v = *(const uint4*)(stash + i * 1024);
                wds[4*i] = v.x; wds[4*i+1] = v.y; wds[4*i+2] = v.z; wds[4*i+3] = v.w;
            }
            #define SV(mf, nf, r) ((r & 1) ? bf2f_hi(wds[(mf)*8+(nf)*2+((r)>>1)]) \
                                           : bf2f_lo(wds[(mf)*8+(nf)*2+((r)>>1)]))
            // bias for this pass's cols
            #pragma unroll
            for (int nf = 0; nf < 4; ++nf) {
                float bv = bfc[512 + wn * 64 + nf * 16 + lr];
                #pragma unroll
                for (int mf = 0; mf < 4; ++mf)
                    #pragma unroll
                    for (int r = 0; r < 4; ++r)
                        acc[mf][nf][r] += bv;
            }
            const bool excl = (wn == 0 && lr == 0);   // stash nf=0 col == 0 (blank)
            if (excl) {
                #pragma unroll
                for (int mf = 0; mf < 4; ++mf)
                    #pragma unroll
                    for (int r = 0; r < 4; ++r)
                        l0sh[wm * 64 + mf * 16 + q * 4 + r] = SV(mf, 0, r);
            }
            // per-row max over cols 1..1023 (8 nf-groups: 4 stash + 4 live)
            #pragma unroll
            for (int mf = 0; mf < 4; ++mf)
                #pragma unroll
                for (int r = 0; r < 4; ++r) {
                    float m = -3.0e38f;
                    #pragma unroll
                    for (int nf = 0; nf < 4; ++nf) {
                        if (!(excl && nf == 0)) m = fmaxf(m, SV(mf, nf, r));
                        m = fmaxf(m, acc[mf][nf][r]);
                    }
                    #pragma unroll
                    for (int s = 1; s < 16; s <<= 1)
                        m = fmaxf(m, __shfl_xor(m, s, 16));
                    if (lr == 0) red[(wm * 64 + mf * 16 + q * 4 + r) * 8 + wn] = m;
                }
            __syncthreads();
            if (tid < 128) {
                float m = red[tid * 8];
                #pragma unroll
                for (int j = 1; j < 8; ++j) m = fmaxf(m, red[tid * 8 + j]);
                Mc[tid] = m;
            }
            __syncthreads();
            #pragma unroll
            for (int mf = 0; mf < 4; ++mf)
                #pragma unroll
                for (int r = 0; r < 4; ++r) {
                    int rl = wm * 64 + mf * 16 + q * 4 + r;
                    float M = Mc[rl];
                    float s = 0.0f;
                    #pragma unroll
                    for (int nf = 0; nf < 4; ++nf) {
                        if (!(excl && nf == 0)) s += __expf(SV(mf, nf, r) - M);
                        s += __expf(acc[mf][nf][r] - M);
                    }
                    #pragma unroll
                    for (int sh = 1; sh < 16; sh <<= 1)
                        s += __shfl_xor(s, sh, 16);
                    if (lr == 0) red[rl * 8 + wn] = s;
                }
            __syncthreads();
            if (tid < 128) {
                float s = red[tid * 8];
                #pragma unroll
                for (int j = 1; j < 8; ++j) s += red[tid * 8 + j];
                float lse = Mc[tid] + __logf(s);
                float l0 = l0sh[tid];
                fin[tid]  = -lse - softplus_f(l0);   // + log_sigmoid(-l0) - lse
                f0sh[tid] = -softplus_f(-l0);        // log_sigmoid(l0)
            }
            __syncthreads();
            // final writes: fix stash cols [0,512) and write live cols [512,1024)
            #pragma unroll
            for (int mf = 0; mf < 4; ++mf)
                #pragma unroll
                for (int r = 0; r < 4; ++r) {
                    int rl = wm * 64 + mf * 16 + q * 4 + r;
                    float fv = fin[rl];
                    float* op = out + (size_t)(r0 + rl) * 1024;
                    #pragma unroll
                    for (int nf = 0; nf < 4; ++nf) {
                        int col = wn * 64 + nf * 16 + lr;
                        op[col] = (col == 0) ? f0sh[rl] : SV(mf, nf, r) + fv;
                        op[512 + col] = acc[mf][nf][r] + fv;
                    }
                }
            #undef SV
        }
    }
}

extern "C" void kernel_launch(void* const* d_in, const int* in_sizes, int n_in,
                              void* d_out, int out_size, void* d_ws, size_t ws_size,
                              hipStream_t stream)
{
    const float* encoder = (const float*)d_in[0]; // [4,400,512]
    const float* decoder = (const float*)d_in[1]; // [4,80,512]
    const float* W_enc   = (const float*)d_in[2]; // [1024,512]
    const float* b_enc   = (const float*)d_in[3]; // [1024]
    const float* W_dec   = (const float*)d_in[4]; // [1024,512]
    const float* b_dec   = (const float*)d_in[5]; // [1024]
    const float* W_fc    = (const float*)d_in[6]; // [1024,1024]
    const float* b_fc    = (const float*)d_in[7]; // [1024]
    float* out = (float*)d_out;

    char* ws = (char*)d_ws;
    float*          enc_f  = (float*)(ws);                  // 1600*1024 f32
    float*          dec_f  = (float*)(ws + 6553600);        // 320*1024 f32
    unsigned short* Wfc_h  = (unsigned short*)(ws + 7864320);   // 1024*1024 bf16
    unsigned short* Wenc_h = (unsigned short*)(ws + 9961472);   // 1024*512 bf16
    unsigned short* Wdec_h = (unsigned short*)(ws + 11010048);  // 1024*512 bf16
    unsigned short* encI_h = (unsigned short*)(ws + 12058624);  // 1600*512 bf16
    unsigned short* decI_h = (unsigned short*)(ws + 13697024);  // 320*512 bf16

    const int nEnc = 4 * 400 * 512, nDec = 4 * 80 * 512;
    const int nWe = 1024 * 512, nWd = 1024 * 512, nWf = 1024 * 1024;
    const int totalF4 = (nEnc + nDec + nWe + nWd + nWf) >> 2;
    k_convert<<<(totalF4 + 255) / 256, 256, 0, stream>>>(
        encoder, decoder, W_enc, W_dec, W_fc,
        encI_h, decI_h, Wenc_h, Wdec_h, Wfc_h,
        nEnc, nDec, nWe, nWd, nWf);

    k_proj<<<dim3(1600 / 32, 8), 256, 0, stream>>>(encI_h, Wenc_h, b_enc, enc_f);
    k_proj<<<dim3(320 / 32, 8), 256, 0, stream>>>(decI_h, Wdec_h, b_dec, dec_f);

    const int SMEM_BYTES = 137216;
    hipFuncSetAttribute(reinterpret_cast<const void*>(k_main),
                        hipFuncAttributeMaxDynamicSharedMemorySize, SMEM_BYTES);
    k_main<<<1000, 1024, SMEM_BYTES, stream>>>(enc_f, dec_f, Wfc_h, b_fc, out);
}

// Round 5
// 688.355 us; speedup vs baseline: 2.7578x; 2.7578x over previous
//
#include <hip/hip_runtime.h>
#include <hip/hip_bf16.h>
#include <cstdint>
#include <cstddef>

typedef short bf16x8 __attribute__((ext_vector_type(8)));
typedef float f32x4 __attribute__((ext_vector_type(4)));

static __device__ __forceinline__ unsigned short f2bf(float f) {
    union { float f; uint32_t u; } c; c.f = f;
    uint32_t r = c.u + 0x7FFFu + ((c.u >> 16) & 1u);
    return (unsigned short)(r >> 16);
}
static __device__ __forceinline__ float bf2f_lo(uint32_t w) {
    union { uint32_t u; float f; } c; c.u = w << 16; return c.f;
}
static __device__ __forceinline__ float bf2f_hi(uint32_t w) {
    union { uint32_t u; float f; } c; c.u = w & 0xffff0000u; return c.f;
}
static __device__ __forceinline__ float fast_tanh(float x) {
    float e = __expf(2.0f * x);
    return 1.0f - 2.0f / (e + 1.0f);
}
static __device__ __forceinline__ float softplus_f(float x) {
    return fmaxf(x, 0.0f) + log1pf(__expf(-fabsf(x)));
}

#define GLOAD_LDS16(g, l) \
    __builtin_amdgcn_global_load_lds((const __attribute__((address_space(1))) void*)(g), \
                                     (__attribute__((address_space(3))) void*)(l), 16, 0, 0)

// ---------------- f32 -> bf16 conversion, 5 segments in one launch ----------
__global__ __launch_bounds__(256) void k_convert(
    const float* __restrict__ s0, const float* __restrict__ s1,
    const float* __restrict__ s2, const float* __restrict__ s3,
    const float* __restrict__ s4,
    unsigned short* __restrict__ d0, unsigned short* __restrict__ d1,
    unsigned short* __restrict__ d2, unsigned short* __restrict__ d3,
    unsigned short* __restrict__ d4,
    int n0, int n1, int n2, int n3, int n4)
{
    int i = blockIdx.x * 256 + threadIdx.x; // float4 index
    int c0 = n0 >> 2, c1 = c0 + (n1 >> 2), c2 = c1 + (n2 >> 2),
        c3 = c2 + (n3 >> 2), c4 = c3 + (n4 >> 2);
    if (i >= c4) return;
    const float* s; unsigned short* d; int j;
    if (i < c0)      { s = s0; d = d0; j = i; }
    else if (i < c1) { s = s1; d = d1; j = i - c0; }
    else if (i < c2) { s = s2; d = d2; j = i - c1; }
    else if (i < c3) { s = s3; d = d3; j = i - c2; }
    else             { s = s4; d = d4; j = i - c3; }
    float4 v = reinterpret_cast<const float4*>(s)[j];
    ushort4 o;
    o.x = f2bf(v.x); o.y = f2bf(v.y); o.z = f2bf(v.z); o.w = f2bf(v.w);
    reinterpret_cast<ushort4*>(d)[j] = o;
}

// ---------------- projection GEMM: out[m,f] = sum_d A[m,d]*W[f,d] + bias[f] --
__global__ __launch_bounds__(256) void k_proj(
    const unsigned short* __restrict__ A,   // [M][512] bf16
    const unsigned short* __restrict__ W,   // [1024][512] bf16
    const float* __restrict__ bias,         // [1024]
    float* __restrict__ out)                // [M][1024] f32
{
    __shared__ unsigned short As[32 * 512];
    const int tid = threadIdx.x;
    const int m0 = blockIdx.x * 32;
    const int c0 = blockIdx.y * 128;
    {
        int row = tid >> 3;
        const unsigned short* src = A + (size_t)(m0 + row) * 512;
        unsigned int base = row * 1024;
        unsigned int sw = (row & 7) << 4;
        #pragma unroll
        for (int c = 0; c < 8; ++c) {
            int col = (tid & 7) * 8 + c * 64;
            bf16x8 v = *reinterpret_cast<const bf16x8*>(src + col);
            *reinterpret_cast<bf16x8*>(
                reinterpret_cast<char*>(As) + ((base + col * 2) ^ sw)) = v;
        }
    }
    __syncthreads();
    const int w = tid >> 6, l = tid & 63;
    const int lr = l & 15, lkb = (l >> 4) * 8;
    f32x4 acc[2][2] = {};
    const int colbase = c0 + w * 32;
    const unsigned short* Wb = W + (size_t)(colbase + lr) * 512 + lkb;
    const unsigned int sw = (lr & 7) << 4;
    for (int ks = 0; ks < 16; ++ks) {
        unsigned int kb = (ks * 32 + lkb) * 2;
        bf16x8 a0 = *reinterpret_cast<const bf16x8*>(
            reinterpret_cast<const char*>(As) + ((lr * 1024 + kb) ^ sw));
        bf16x8 a1 = *reinterpret_cast<const bf16x8*>(
            reinterpret_cast<const char*>(As) + (((16 + lr) * 1024 + kb) ^ sw));
        #pragma unroll
        for (int nf = 0; nf < 2; ++nf) {
            bf16x8 b = *reinterpret_cast<const bf16x8*>(Wb + nf * 16 * 512 + ks * 32);
            acc[0][nf] = __builtin_amdgcn_mfma_f32_16x16x32_bf16(a0, b, acc[0][nf], 0, 0, 0);
            acc[1][nf] = __builtin_amdgcn_mfma_f32_16x16x32_bf16(a1, b, acc[1][nf], 0, 0, 0);
        }
    }
    const int qr = (l >> 4) * 4;
    #pragma unroll
    for (int nf = 0; nf < 2; ++nf) {
        int col = colbase + nf * 16 + lr;
        float bv = bias[col];
        #pragma unroll
        for (int mf = 0; mf < 2; ++mf)
            #pragma unroll
            for (int r = 0; r < 4; ++r)
                out[(size_t)(m0 + mf * 16 + qr + r) * 1024 + col] = acc[mf][nf][r] + bv;
    }
}

// ---------------- A = tanh(enc+dec) -> bf16, interleaved into out -----------
// Row r of out (4096 B): bytes [0,2048) hold A[r][0..1023] bf16.
__global__ __launch_bounds__(256) void k_tanhA(
    const float* __restrict__ enc_f,   // [1600][1024]
    const float* __restrict__ dec_f,   // [320][1024]
    char* __restrict__ outb)
{
    const int NG = 128000 * 128;       // 16B groups
    for (int g = blockIdx.x * 256 + threadIdx.x; g < NG; g += gridDim.x * 256) {
        int row = g >> 7, c8 = g & 127;
        int bt = row / 80;
        int u = row - bt * 80;
        int b = bt / 400;
        const float* ep = enc_f + (size_t)bt * 1024 + c8 * 8;
        const float* dp = dec_f + (size_t)(b * 80 + u) * 1024 + c8 * 8;
        float4 e0 = *(const float4*)ep, e1 = *(const float4*)(ep + 4);
        float4 f0 = *(const float4*)dp, f1 = *(const float4*)(dp + 4);
        uint4 pk;
        pk.x = (uint32_t)f2bf(fast_tanh(e0.x + f0.x)) | ((uint32_t)f2bf(fast_tanh(e0.y + f0.y)) << 16);
        pk.y = (uint32_t)f2bf(fast_tanh(e0.z + f0.z)) | ((uint32_t)f2bf(fast_tanh(e0.w + f0.w)) << 16);
        pk.z = (uint32_t)f2bf(fast_tanh(e1.x + f1.x)) | ((uint32_t)f2bf(fast_tanh(e1.y + f1.y)) << 16);
        pk.w = (uint32_t)f2bf(fast_tanh(e1.z + f1.z)) | ((uint32_t)f2bf(fast_tanh(e1.w + f1.w)) << 16);
        *(uint4*)(outb + (size_t)row * 4096 + c8 * 16) = pk;
    }
}

// ---------------- main GEMM: logits = A @ Wfc^T + bias (bf16 out) -----------
// m97 structure: 128x128 tile, BK=64, 256 thr (4 waves 2x2), single-buffer
// 32KB LDS, global_load_lds w16 with pre-swizzled source, XOR-swizzled reads.
// Swapped MFMA operands -> lane holds 4 consecutive vocab values (8B stores).
// Grid 8000 = 8 XCD chunks x (125 M-panels x 8 N-panels, N fastest) so all
// N-panels of an M-panel share one XCD's L2 (A fetched from HBM once).
__global__ __launch_bounds__(256, 4) void k_gemm(
    const unsigned short* __restrict__ Wfc,   // [1024][1024] bf16
    const float* __restrict__ bfc,            // [1024]
    char* __restrict__ outb)                  // A in [0,2048), logits out [2048,4096)
{
    __shared__ char As[16384];
    __shared__ char Bs[16384];
    const int tid = threadIdx.x;
    const int w = tid >> 6, l = tid & 63;
    const int lr = l & 15, q = l >> 4;
    const int wm = w >> 1, wn = w & 1;

    const int bid = (int)blockIdx.x;
    const int xcd = bid & 7, loc = bid >> 3;
    const size_t R0 = (size_t)(xcd * 125 + (loc >> 3)) * 128;
    const int n0 = (loc & 7) * 128;

    // staging: 4 A-chunks + 4 B-chunks per thread, 16B each. LDS dest linear;
    // source address carries the inverse swizzle (same involution as reads).
    const char* srcA[4]; const char* srcB[4];
    unsigned dst[4];
    #pragma unroll
    for (int i = 0; i < 4; ++i) {
        unsigned d = tid * 16 + i * 4096;
        unsigned L = d ^ (((d >> 7) & 7u) << 4);
        unsigned row = L >> 7, kb = L & 127u;
        dst[i] = d;
        srcA[i] = outb + (R0 + row) * 4096 + kb;
        srcB[i] = (const char*)Wfc + (size_t)(n0 + row) * 2048 + kb;
    }

    const unsigned key = (unsigned)((lr & 7) << 4);
    unsigned aoff[4], boff[4];
    #pragma unroll
    for (int mf = 0; mf < 4; ++mf) aoff[mf] = (unsigned)((wm * 64 + mf * 16 + lr) * 128);
    #pragma unroll
    for (int nf = 0; nf < 4; ++nf) boff[nf] = (unsigned)((wn * 64 + nf * 16 + lr) * 128);

    f32x4 acc[4][4] = {};   // [nf][mf]

    for (int ks = 0; ks < 16; ++ks) {
        #pragma unroll
        for (int i = 0; i < 4; ++i) {
            GLOAD_LDS16(srcA[i] + ks * 128, As + dst[i]);
            GLOAD_LDS16(srcB[i] + ks * 128, Bs + dst[i]);
        }
        __syncthreads();
        #pragma unroll
        for (int kk = 0; kk < 2; ++kk) {
            const unsigned ko = (unsigned)(kk * 64 + q * 16) ^ key;
            bf16x8 af[4], bf[4];
            #pragma unroll
            for (int mf = 0; mf < 4; ++mf) af[mf] = *(const bf16x8*)(As + aoff[mf] + ko);
            #pragma unroll
            for (int nf = 0; nf < 4; ++nf) bf[nf] = *(const bf16x8*)(Bs + boff[nf] + ko);
            #pragma unroll
            for (int nf = 0; nf < 4; ++nf)
                #pragma unroll
                for (int mf = 0; mf < 4; ++mf)
                    acc[nf][mf] = __builtin_amdgcn_mfma_f32_16x16x32_bf16(
                        bf[nf], af[mf], acc[nf][mf], 0, 0, 0);
        }
        __syncthreads();
    }

    // epilogue: bias + pack bf16 + 8B stores (4 consecutive vocab per lane)
    const int vq = n0 + wn * 64 + q * 4;
    #pragma unroll
    for (int nf = 0; nf < 4; ++nf) {
        float4 bv = *(const float4*)(bfc + vq + nf * 16);
        #pragma unroll
        for (int mf = 0; mf < 4; ++mf) {
            f32x4 v = acc[nf][mf];
            uint2 pk;
            pk.x = (uint32_t)f2bf(v[0] + bv.x) | ((uint32_t)f2bf(v[1] + bv.y) << 16);
            pk.y = (uint32_t)f2bf(v[2] + bv.z) | ((uint32_t)f2bf(v[3] + bv.w) << 16);
            size_t m = R0 + (size_t)(wm * 64 + mf * 16 + lr);
            *(uint2*)(outb + m * 4096 + 2048 + (size_t)(vq + nf * 16) * 2) = pk;
        }
    }
}

// ---------------- softmax/blank epilogue pass --------------------------------
// One wave per row: read 1024 bf16 logits (bytes [2048,4096) of the row),
// compute log_sigmoid(blank) + log_softmax over cols 1..1023, write full
// 1024 f32 row (overwrites the A/logit stash).
__global__ __launch_bounds__(256) void k_softmax(char* __restrict__ outb)
{
    const int row = blockIdx.x * 4 + (threadIdx.x >> 6);
    const int l = threadIdx.x & 63;
    const char* lp = outb + (size_t)row * 4096 + 2048 + l * 32;
    uint4 wa = *(const uint4*)lp;
    uint4 wb = *(const uint4*)(lp + 16);
    float v[16];
    uint32_t wd[8] = { wa.x, wa.y, wa.z, wa.w, wb.x, wb.y, wb.z, wb.w };
    #pragma unroll
    for (int i = 0; i < 8; ++i) { v[2*i] = bf2f_lo(wd[i]); v[2*i+1] = bf2f_hi(wd[i]); }

    float l0 = __shfl(v[0], 0);
    float m = (l == 0) ? -3.0e38f : v[0];
    #pragma unroll
    for (int i = 1; i < 16; ++i) m = fmaxf(m, v[i]);
    #pragma unroll
    for (int s = 1; s < 64; s <<= 1) m = fmaxf(m, __shfl_xor(m, s));
    float s = (l == 0) ? 0.0f : __expf(v[0] - m);
    #pragma unroll
    for (int i = 1; i < 16; ++i) s += __expf(v[i] - m);
    #pragma unroll
    for (int sh = 1; sh < 64; sh <<= 1) s += __shfl_xor(s, sh);

    float lse = m + __logf(s);
    float fin = -lse - softplus_f(l0);     // log_sigmoid(-l0) - lse
    float f0v = -softplus_f(-l0);          // log_sigmoid(l0)

    float* op = (float*)(outb + (size_t)row * 4096) + l * 16;
    #pragma unroll
    for (int c = 0; c < 4; ++c) {
        float4 o;
        o.x = v[4*c+0] + fin; o.y = v[4*c+1] + fin;
        o.z = v[4*c+2] + fin; o.w = v[4*c+3] + fin;
        if (l == 0 && c == 0) o.x = f0v;
        *(float4*)(op + 4*c) = o;
    }
}

extern "C" void kernel_launch(void* const* d_in, const int* in_sizes, int n_in,
                              void* d_out, int out_size, void* d_ws, size_t ws_size,
                              hipStream_t stream)
{
    const float* encoder = (const float*)d_in[0]; // [4,400,512]
    const float* decoder = (const float*)d_in[1]; // [4,80,512]
    const float* W_enc   = (const float*)d_in[2]; // [1024,512]
    const float* b_enc   = (const float*)d_in[3]; // [1024]
    const float* W_dec   = (const float*)d_in[4]; // [1024,512]
    const float* b_dec   = (const float*)d_in[5]; // [1024]
    const float* W_fc    = (const float*)d_in[6]; // [1024,1024]
    const float* b_fc    = (const float*)d_in[7]; // [1024]
    char* outb = (char*)d_out;

    char* ws = (char*)d_ws;
    float*          enc_f  = (float*)(ws);                      // 1600*1024 f32
    float*          dec_f  = (float*)(ws + 6553600);            // 320*1024 f32
    unsigned short* Wfc_h  = (unsigned short*)(ws + 7864320);   // 1024*1024 bf16
    unsigned short* Wenc_h = (unsigned short*)(ws + 9961472);   // 1024*512 bf16
    unsigned short* Wdec_h = (unsigned short*)(ws + 11010048);  // 1024*512 bf16
    unsigned short* encI_h = (unsigned short*)(ws + 12058624);  // 1600*512 bf16
    unsigned short* decI_h = (unsigned short*)(ws + 13697024);  // 320*512 bf16

    const int nEnc = 4 * 400 * 512, nDec = 4 * 80 * 512;
    const int nWe = 1024 * 512, nWd = 1024 * 512, nWf = 1024 * 1024;
    const int totalF4 = (nEnc + nDec + nWe + nWd + nWf) >> 2;
    k_convert<<<(totalF4 + 255) / 256, 256, 0, stream>>>(
        encoder, decoder, W_enc, W_dec, W_fc,
        encI_h, decI_h, Wenc_h, Wdec_h, Wfc_h,
        nEnc, nDec, nWe, nWd, nWf);

    k_proj<<<dim3(1600 / 32, 8), 256, 0, stream>>>(encI_h, Wenc_h, b_enc, enc_f);
    k_proj<<<dim3(320 / 32, 8), 256, 0, stream>>>(decI_h, Wdec_h, b_dec, dec_f);

    k_tanhA<<<4096, 256, 0, stream>>>(enc_f, dec_f, outb);
    k_gemm<<<8000, 256, 0, stream>>>(Wfc_h, b_fc, outb);
    k_softmax<<<32000, 256, 0, stream>>>(outb);
}